// Round 1
// baseline (1932.996 us; speedup 1.0000x reference)
//
#include <hip/hip_runtime.h>
#include <stdint.h>

#define DD  128   // D
#define G2D 256   // 2*D
#define G4D 512   // 4*D

typedef float  f32x4  __attribute__((ext_vector_type(4)));
typedef short  s16x8  __attribute__((ext_vector_type(8)));
typedef __bf16 bf16x8 __attribute__((ext_vector_type(8)));

__device__ __forceinline__ short f2bf(float f) {
  unsigned u = __builtin_bit_cast(unsigned, f);
  u += 0x7FFFu + ((u >> 16) & 1u);   // RNE
  return (short)(u >> 16);
}

__device__ __forceinline__ float sigmoidf_(float x) {
  return 1.f / (1.f + __expf(-x));
}
__device__ __forceinline__ float tanhf_(float x) {
  x = fminf(fmaxf(x, -15.f), 15.f);
  float e = __expf(2.f * x);
  return (e - 1.f) / (e + 1.f);
}

// seg[g] = lower_bound(ind, g) for g in [0..G]; graph_indicator is sorted.
__global__ void seg_kernel(const int* __restrict__ ind, int* __restrict__ seg,
                           int N, int G) {
  int g = blockIdx.x * blockDim.x + threadIdx.x;
  if (g > G) return;
  int lo = 0, hi = N;
  while (lo < hi) {
    int mid = (lo + hi) >> 1;
    if (ind[mid] < g) lo = mid + 1; else hi = mid;
  }
  seg[g] = lo;
}

// WT[n][k] = bf16(W[k][n]); W is [256,512] fp32, WT is [512,256] bf16
__global__ void wconv_kernel(const float* __restrict__ W, short* __restrict__ WT) {
  int idx = blockIdx.x * blockDim.x + threadIdx.x;  // 131072 threads
  int n = idx & (G4D - 1);
  int k = idx >> 9;
  WT[(size_t)n * G2D + k] = f2bf(W[(size_t)k * G4D + n]);
}

// One wave per graph. Half-wave per node (float4/lane over 128 feats).
// Online softmax (flash-style): single pass over the segment's rows.
// Reads carry = ce[g][0:128], writes readout = ce[g][128:256].
__global__ void __launch_bounds__(256) passa_kernel(
    const float* __restrict__ nf, float* __restrict__ ce,
    const int* __restrict__ seg, int G) {
  int wid = (blockIdx.x * blockDim.x + threadIdx.x) >> 6;
  if (wid >= G) return;
  int lane = threadIdx.x & 63;
  int half = lane >> 5;
  int hl   = lane & 31;
  int s0 = seg[wid], s1 = seg[wid + 1];
  int n  = s1 - s0;
  float* cerow = ce + (size_t)wid * G2D;
  if (n == 0) {                       // empty graph: readout = 0
    if (half == 0) { f32x4 z = {0.f,0.f,0.f,0.f}; *(f32x4*)(cerow + DD + hl * 4) = z; }
    return;
  }
  f32x4 c4 = *(const f32x4*)(cerow + hl * 4);
  float m = -INFINITY, l = 0.f;
  f32x4 acc = {0.f, 0.f, 0.f, 0.f};
  const float* base = nf + (size_t)s0 * DD + hl * 4;
  for (int i = 0; i < n; i += 2) {
    int j = i + half;
    if (j < n) {                       // uniform per half-wave
      f32x4 x = *(const f32x4*)(base + (size_t)j * DD);
      float s = x.x * c4.x + x.y * c4.y + x.z * c4.z + x.w * c4.w;
      #pragma unroll
      for (int off = 1; off < 32; off <<= 1) s += __shfl_xor(s, off, 64);
      float nm = fmaxf(m, s);
      float sc = __expf(m - nm);       // exp(-inf)=0 on first iter
      float p  = __expf(s - nm);
      l = l * sc + p;
      acc.x = acc.x * sc + p * x.x;
      acc.y = acc.y * sc + p * x.y;
      acc.z = acc.z * sc + p * x.z;
      acc.w = acc.w * sc + p * x.w;
      m = nm;
    }
  }
  // merge the two half-wave softmax states
  float m2 = __shfl_xor(m, 32, 64);
  float l2 = __shfl_xor(l, 32, 64);
  f32x4 a2;
  a2.x = __shfl_xor(acc.x, 32, 64);
  a2.y = __shfl_xor(acc.y, 32, 64);
  a2.z = __shfl_xor(acc.z, 32, 64);
  a2.w = __shfl_xor(acc.w, 32, 64);
  float M  = fmaxf(m, m2);             // finite since n >= 1
  float e1 = __expf(m - M);
  float e2 = __expf(m2 - M);
  float L  = l * e1 + l2 * e2;
  float inv = 1.f / L;
  if (half == 0) {
    f32x4 r;
    r.x = (acc.x * e1 + a2.x * e2) * inv;
    r.y = (acc.y * e1 + a2.y * e2) * inv;
    r.z = (acc.z * e1 + a2.z * e2) * inv;
    r.w = (acc.w * e1 + a2.w * e2) * inv;
    *(f32x4*)(cerow + DD + hl * 4) = r;
  }
}

// Fused z = [carry|readout] @ W + b and LSTM gates.
// Block = 16 rows of G; 4 waves; wave w owns cols w*32..w*32+31 of all 4 gates.
// A staged in LDS as bf16 (padded +8 to dodge bank conflicts), B = WT from L2.
__global__ void __launch_bounds__(256) lstm_kernel(
    float* __restrict__ ce, const short* __restrict__ WT,
    const float* __restrict__ bias, float* __restrict__ mem, int G) {
  __shared__ __align__(16) short As[16][264];
  int m0 = blockIdx.x * 16;
  int t  = threadIdx.x;
  #pragma unroll
  for (int rep = 0; rep < 4; rep++) {
    int idx = rep * 256 + t;          // 0..1023 float4 slots (16 rows x 64)
    int row = idx >> 6;
    int cv  = idx & 63;
    int g   = m0 + row;
    f32x4 v = {0.f, 0.f, 0.f, 0.f};
    if (g < G) v = *(const f32x4*)(ce + (size_t)g * G2D + cv * 4);
    As[row][cv * 4 + 0] = f2bf(v.x);
    As[row][cv * 4 + 1] = f2bf(v.y);
    As[row][cv * 4 + 2] = f2bf(v.z);
    As[row][cv * 4 + 3] = f2bf(v.w);
  }
  __syncthreads();
  int wid  = t >> 6;
  int lane = t & 63;
  int quad = lane >> 4;
  int l16  = lane & 15;
  int cb   = wid * 32;
  f32x4 zero4 = {0.f, 0.f, 0.f, 0.f};
  f32x4 acc[4][2];
  #pragma unroll
  for (int gi = 0; gi < 4; gi++)
    #pragma unroll
    for (int ns = 0; ns < 2; ns++) acc[gi][ns] = zero4;
  #pragma unroll
  for (int kc = 0; kc < 8; kc++) {
    int k0 = kc * 32 + quad * 8;
    s16x8 a = *(const s16x8*)(&As[l16][k0]);
    #pragma unroll
    for (int gi = 0; gi < 4; gi++) {
      #pragma unroll
      for (int ns = 0; ns < 2; ns++) {
        int ncol = gi * DD + cb + ns * 16 + l16;
        s16x8 b = *(const s16x8*)(WT + (size_t)ncol * G2D + k0);
        acc[gi][ns] = __builtin_amdgcn_mfma_f32_16x16x32_bf16(
            __builtin_bit_cast(bf16x8, a), __builtin_bit_cast(bf16x8, b),
            acc[gi][ns], 0, 0, 0);
      }
    }
  }
  // epilogue: gates + state update. C/D layout: col=lane&15, row=quad*4+reg.
  #pragma unroll
  for (int ns = 0; ns < 2; ns++) {
    int col = cb + ns * 16 + l16;
    float bu = bias[0 * DD + col];
    float bf = bias[1 * DD + col];
    float bc = bias[2 * DD + col];
    float bo = bias[3 * DD + col];
    #pragma unroll
    for (int r = 0; r < 4; r++) {
      int g = m0 + quad * 4 + r;
      if (g < G) {
        float u = acc[0][ns][r] + bu;
        float f = acc[1][ns][r] + bf;
        float c = acc[2][ns][r] + bc;
        float o = acc[3][ns][r] + bo;
        float mo = mem[(size_t)g * DD + col];
        float mn = sigmoidf_(f) * mo + sigmoidf_(u) * tanhf_(c);
        mem[(size_t)g * DD + col] = mn;
        ce[(size_t)g * G2D + col] = sigmoidf_(o) * tanhf_(mn);
      }
    }
  }
}

extern "C" void kernel_launch(void* const* d_in, const int* in_sizes, int n_in,
                              void* d_out, int out_size, void* d_ws, size_t ws_size,
                              hipStream_t stream) {
  const float* nf   = (const float*)d_in[0];
  const int*   ind  = (const int*)d_in[1];
  const float* W    = (const float*)d_in[2];
  const float* bias = (const float*)d_in[3];
  int N = in_sizes[1];
  int G = out_size / G2D;   // 25000

  char* ws = (char*)d_ws;
  size_t off = 0;
  float* ce  = (float*)(ws + off); off += (size_t)G * G2D * 4;   // carry|readout
  float* mem = (float*)(ws + off); off += (size_t)G * DD * 4;    // memory state
  short* WT  = (short*)(ws + off); off += (size_t)G2D * G4D * 2; // W^T bf16
  int*   seg = (int*)(ws + off);   off += (size_t)(G + 1) * 4;
  (void)ws_size; (void)n_in;

  // zero carry_evolved + memory (contiguous)
  hipMemsetAsync(ce, 0, (size_t)G * G2D * 4 + (size_t)G * DD * 4, stream);
  seg_kernel<<<(G + 256) / 256, 256, 0, stream>>>(ind, seg, N, G);
  wconv_kernel<<<(G2D * G4D) / 256, 256, 0, stream>>>(W, WT);

  int pa_blocks   = (G + 3) / 4;     // 1 wave per graph, 4 waves/block
  int lstm_blocks = (G + 15) / 16;
  for (int step = 0; step < 8; step++) {
    passa_kernel<<<pa_blocks, 256, 0, stream>>>(nf, ce, seg, G);
    if (step < 7)   // output doesn't depend on the last LSTM update
      lstm_kernel<<<lstm_blocks, 256, 0, stream>>>(ce, WT, bias, mem, G);
  }
  hipMemcpyAsync(d_out, ce, (size_t)out_size * 4, hipMemcpyDeviceToDevice, stream);
}

// Round 2
// 1587.225 us; speedup vs baseline: 1.2178x; 1.2178x over previous
//
#include <hip/hip_runtime.h>
#include <stdint.h>

#define DD  128   // D
#define G2D 256   // 2*D
#define G4D 512   // 4*D

typedef float  f32x4  __attribute__((ext_vector_type(4)));
typedef short  s16x8  __attribute__((ext_vector_type(8)));
typedef __bf16 bf16x8 __attribute__((ext_vector_type(8)));

__device__ __forceinline__ short f2bf(float f) {
  unsigned u = __builtin_bit_cast(unsigned, f);
  u += 0x7FFFu + ((u >> 16) & 1u);   // RNE
  return (short)(u >> 16);
}
__device__ __forceinline__ float bf2f(short s) {
  unsigned u = ((unsigned)(unsigned short)s) << 16;
  return __builtin_bit_cast(float, u);
}
__device__ __forceinline__ float sigmoidf_(float x) {
  return 1.f / (1.f + __expf(-x));
}
__device__ __forceinline__ float tanhf_(float x) {
  x = fminf(fmaxf(x, -15.f), 15.f);
  float e = __expf(2.f * x);
  return (e - 1.f) / (e + 1.f);
}

// seg[g] = lower_bound(ind, g) for g in [0..G]; graph_indicator is sorted.
__global__ void seg_kernel(const int* __restrict__ ind, int* __restrict__ seg,
                           int N, int G) {
  int g = blockIdx.x * blockDim.x + threadIdx.x;
  if (g > G) return;
  int lo = 0, hi = N;
  while (lo < hi) {
    int mid = (lo + hi) >> 1;
    if (ind[mid] < g) lo = mid + 1; else hi = mid;
  }
  seg[g] = lo;
}

// node_feature fp32 -> bf16, 8 elems/thread (32B read, 16B write per lane)
__global__ void nfconv_kernel(const float* __restrict__ nf,
                              short* __restrict__ nfb) {
  size_t idx = (size_t)blockIdx.x * blockDim.x + threadIdx.x;
  const f32x4* src = (const f32x4*)nf + idx * 2;
  f32x4 a = src[0], b = src[1];
  s16x8 o;
  o[0] = f2bf(a.x); o[1] = f2bf(a.y); o[2] = f2bf(a.z); o[3] = f2bf(a.w);
  o[4] = f2bf(b.x); o[5] = f2bf(b.y); o[6] = f2bf(b.z); o[7] = f2bf(b.w);
  ((s16x8*)nfb)[idx] = o;
}

// WT[n][k] = bf16(W[k][n]); W is [256,512] fp32, WT is [512,256] bf16
__global__ void wconv_kernel(const float* __restrict__ W, short* __restrict__ WT) {
  int idx = blockIdx.x * blockDim.x + threadIdx.x;  // 131072 threads
  int n = idx & (G4D - 1);
  int k = idx >> 9;
  WT[(size_t)n * G2D + k] = f2bf(W[(size_t)k * G4D + n]);
}

// One wave per graph; 4 independent 16-lane online-softmax groups (one row
// each per iteration, 16B bf16 loads/lane, 4-shuffle reduce). Guard-free
// main loop (n>>2 iters) + remainder, merged across groups at the end.
__global__ void __launch_bounds__(256) passa_kernel(
    const short* __restrict__ nfb, float* __restrict__ ce,
    const int* __restrict__ seg, int G) {
  int wid = (blockIdx.x * blockDim.x + threadIdx.x) >> 6;
  if (wid >= G) return;
  int lane = threadIdx.x & 63;
  int gq = lane >> 4;     // group 0..3
  int sl = lane & 15;     // sub-lane: features sl*8 .. sl*8+7
  int s0 = seg[wid], s1 = seg[wid + 1];
  int n  = s1 - s0;
  float* cerow = ce + (size_t)wid * G2D;
  if (n == 0) {                       // empty graph: readout = 0
    if (gq == 0) {
      f32x4 z = {0.f, 0.f, 0.f, 0.f};
      *(f32x4*)(cerow + DD + sl * 8)     = z;
      *(f32x4*)(cerow + DD + sl * 8 + 4) = z;
    }
    return;
  }
  f32x4 c0 = *(const f32x4*)(cerow + sl * 8);
  f32x4 c1 = *(const f32x4*)(cerow + sl * 8 + 4);
  float m = -1e30f, l = 0.f;
  float acc[8];
  #pragma unroll
  for (int k = 0; k < 8; k++) acc[k] = 0.f;
  const short* base = nfb + (size_t)s0 * DD + sl * 8;

  auto body = [&](int j) {
    s16x8 xr = *(const s16x8*)(base + (size_t)j * DD);
    float xf[8];
    #pragma unroll
    for (int k = 0; k < 8; k++) xf[k] = bf2f(xr[k]);
    float s = xf[0]*c0.x + xf[1]*c0.y + xf[2]*c0.z + xf[3]*c0.w
            + xf[4]*c1.x + xf[5]*c1.y + xf[6]*c1.z + xf[7]*c1.w;
    #pragma unroll
    for (int off = 1; off < 16; off <<= 1) s += __shfl_xor(s, off, 64);
    float nm = fmaxf(m, s);
    float sc = __expf(m - nm);   // exp(-huge)=0 on first active iter
    float p  = __expf(s - nm);
    l = l * sc + p;
    #pragma unroll
    for (int k = 0; k < 8; k++) acc[k] = acc[k] * sc + p * xf[k];
    m = nm;
  };

  int nfull = n >> 2;
  #pragma unroll 2
  for (int i = 0; i < nfull; i++) body(i * 4 + gq);
  int rem = n & 3;
  if (gq < rem) body(nfull * 4 + gq);

  // merge the 4 group states (xor 16, then xor 32)
  #pragma unroll
  for (int w = 16; w <= 32; w <<= 1) {
    float m2 = __shfl_xor(m, w, 64);
    float l2 = __shfl_xor(l, w, 64);
    float M  = fmaxf(m, m2);
    float e1 = __expf(m - M);
    float e2 = __expf(m2 - M);
    l = l * e1 + l2 * e2;
    #pragma unroll
    for (int k = 0; k < 8; k++) {
      float a2 = __shfl_xor(acc[k], w, 64);
      acc[k] = acc[k] * e1 + a2 * e2;
    }
    m = M;
  }
  if (gq == 0) {
    float inv = 1.f / l;            // l > 0 since n >= 1
    f32x4 r0, r1;
    r0.x = acc[0]*inv; r0.y = acc[1]*inv; r0.z = acc[2]*inv; r0.w = acc[3]*inv;
    r1.x = acc[4]*inv; r1.y = acc[5]*inv; r1.z = acc[6]*inv; r1.w = acc[7]*inv;
    *(f32x4*)(cerow + DD + sl * 8)     = r0;
    *(f32x4*)(cerow + DD + sl * 8 + 4) = r1;
  }
}

// Fused z = [carry|readout] @ W + b and LSTM gates.
// Block = 16 rows of G; 4 waves; wave w owns cols w*32..w*32+31 of all 4 gates.
__global__ void __launch_bounds__(256) lstm_kernel(
    float* __restrict__ ce, const short* __restrict__ WT,
    const float* __restrict__ bias, float* __restrict__ mem, int G) {
  __shared__ __align__(16) short As[16][264];
  int m0 = blockIdx.x * 16;
  int t  = threadIdx.x;
  #pragma unroll
  for (int rep = 0; rep < 4; rep++) {
    int idx = rep * 256 + t;          // 0..1023 float4 slots (16 rows x 64)
    int row = idx >> 6;
    int cv  = idx & 63;
    int g   = m0 + row;
    f32x4 v = {0.f, 0.f, 0.f, 0.f};
    if (g < G) v = *(const f32x4*)(ce + (size_t)g * G2D + cv * 4);
    As[row][cv * 4 + 0] = f2bf(v.x);
    As[row][cv * 4 + 1] = f2bf(v.y);
    As[row][cv * 4 + 2] = f2bf(v.z);
    As[row][cv * 4 + 3] = f2bf(v.w);
  }
  __syncthreads();
  int wid  = t >> 6;
  int lane = t & 63;
  int quad = lane >> 4;
  int l16  = lane & 15;
  int cb   = wid * 32;
  f32x4 zero4 = {0.f, 0.f, 0.f, 0.f};
  f32x4 acc[4][2];
  #pragma unroll
  for (int gi = 0; gi < 4; gi++)
    #pragma unroll
    for (int ns = 0; ns < 2; ns++) acc[gi][ns] = zero4;
  #pragma unroll
  for (int kc = 0; kc < 8; kc++) {
    int k0 = kc * 32 + quad * 8;
    s16x8 a = *(const s16x8*)(&As[l16][k0]);
    #pragma unroll
    for (int gi = 0; gi < 4; gi++) {
      #pragma unroll
      for (int ns = 0; ns < 2; ns++) {
        int ncol = gi * DD + cb + ns * 16 + l16;
        s16x8 b = *(const s16x8*)(WT + (size_t)ncol * G2D + k0);
        acc[gi][ns] = __builtin_amdgcn_mfma_f32_16x16x32_bf16(
            __builtin_bit_cast(bf16x8, a), __builtin_bit_cast(bf16x8, b),
            acc[gi][ns], 0, 0, 0);
      }
    }
  }
  // epilogue: gates + state update. C/D layout: col=lane&15, row=quad*4+reg.
  #pragma unroll
  for (int ns = 0; ns < 2; ns++) {
    int col = cb + ns * 16 + l16;
    float bu = bias[0 * DD + col];
    float bf = bias[1 * DD + col];
    float bc = bias[2 * DD + col];
    float bo = bias[3 * DD + col];
    #pragma unroll
    for (int r = 0; r < 4; r++) {
      int g = m0 + quad * 4 + r;
      if (g < G) {
        float u = acc[0][ns][r] + bu;
        float f = acc[1][ns][r] + bf;
        float c = acc[2][ns][r] + bc;
        float o = acc[3][ns][r] + bo;
        float mo = mem[(size_t)g * DD + col];
        float mn = sigmoidf_(f) * mo + sigmoidf_(u) * tanhf_(c);
        mem[(size_t)g * DD + col] = mn;
        ce[(size_t)g * G2D + col] = sigmoidf_(o) * tanhf_(mn);
      }
    }
  }
}

extern "C" void kernel_launch(void* const* d_in, const int* in_sizes, int n_in,
                              void* d_out, int out_size, void* d_ws, size_t ws_size,
                              hipStream_t stream) {
  const float* nf   = (const float*)d_in[0];
  const int*   ind  = (const int*)d_in[1];
  const float* W    = (const float*)d_in[2];
  const float* bias = (const float*)d_in[3];
  int N = in_sizes[1];
  int G = out_size / G2D;   // 25000

  char* ws = (char*)d_ws;
  size_t off = 0;
  float* ce  = (float*)(ws + off); off += (size_t)G * G2D * 4;   // carry|readout
  float* mem = (float*)(ws + off); off += (size_t)G * DD * 4;    // memory state
  short* WT  = (short*)(ws + off); off += (size_t)G2D * G4D * 2; // W^T bf16
  int*   seg = (int*)(ws + off);   off += (size_t)(G + 1) * 4;
  off = (off + 255) & ~(size_t)255;
  short* nfb = (short*)(ws + off); off += (size_t)N * DD * 2;    // nf bf16
  (void)ws_size; (void)n_in;

  // nf -> bf16 (dominant-cost reducer), then zero carry_evolved + memory
  nfconv_kernel<<<(int)(((size_t)N * DD / 8 + 255) / 256), 256, 0, stream>>>(nf, nfb);
  hipMemsetAsync(ce, 0, (size_t)G * G2D * 4 + (size_t)G * DD * 4, stream);
  seg_kernel<<<(G + 256) / 256, 256, 0, stream>>>(ind, seg, N, G);
  wconv_kernel<<<(G2D * G4D) / 256, 256, 0, stream>>>(W, WT);

  int pa_blocks   = (G + 3) / 4;     // 1 wave per graph, 4 waves/block
  int lstm_blocks = (G + 15) / 16;
  for (int step = 0; step < 8; step++) {
    passa_kernel<<<pa_blocks, 256, 0, stream>>>(nfb, ce, seg, G);
    if (step < 7)   // output doesn't depend on the last LSTM update
      lstm_kernel<<<lstm_blocks, 256, 0, stream>>>(ce, WT, bias, mem, G);
  }
  hipMemcpyAsync(d_out, ce, (size_t)out_size * 4, hipMemcpyDeviceToDevice, stream);
}